// Round 6
// baseline (168.126 us; speedup 1.0000x reference)
//
#include <hip/hip_runtime.h>
#include <cstdint>

#define NW 10
#define NOPS 30
#define MAXG 48

// History: R1-R4 failed with O(1) absmax under FOUR consumption models because
// the SeedSequence pool mix used XOR instead of SUBTRACTION (caught by R5's
// compile-time canary). R6: mix() fixed; consumption = all-32-bit Lemire
// (verified against numpy distributions.c: random_bounded_uint64 single-draw
// AND _fill both downshift to bounded_lemire_uint32 for rng <= 0xFFFFFFFF;
// Generator._shuffle_raw uses random_bounded_uint64(0,i,0,0), NOT
// random_interval).

// ---------------------------------------------------------------------------
struct Gates {
  int n;
  int type[MAXG];
  int a[MAXG];   // 1q: bit pos of wire; cnot: bit pos of control
  int b[MAXG];   // cnot: bit pos of target
  int slot[MAXG];// 1q: matrix slot in ws
};

struct PrepInfo {
  int kinds[NOPS]; // 0 rx, 1 ry, 2 rz, 3 cnot (no matrix)
};

// ---------------------------------------------------------------------------
// Prep kernel: gate matrices + MLP collapse (audited; unchanged).
// ---------------------------------------------------------------------------
__global__ __launch_bounds__(64) void prep_kernel(
    const float* __restrict__ rand_params,
    const float* __restrict__ rx_theta, const float* __restrict__ ry_theta,
    const float* __restrict__ w0, const float* __restrict__ b0,
    const float* __restrict__ w1, const float* __restrict__ b1,
    const float* __restrict__ w2, const float* __restrict__ b2,
    const float* __restrict__ w3, const float* __restrict__ b3,
    float* __restrict__ gmats, float* __restrict__ weff,
    PrepInfo info)
{
  const int tid = threadIdx.x;
  __shared__ float r2[32];
  __shared__ float r1[64];

  if (tid < NOPS && info.kinds[tid] != 3) {
    float t = rand_params[tid] * 0.5f;
    float c = cosf(t), s = sinf(t);
    float* M = gmats + tid * 8;
    int k = info.kinds[tid];
    if (k == 0) {        // RX
      M[0]=c;  M[1]=0.f; M[2]=0.f; M[3]=-s;
      M[4]=0.f; M[5]=-s; M[6]=c;  M[7]=0.f;
    } else if (k == 1) { // RY
      M[0]=c;  M[1]=0.f; M[2]=-s; M[3]=0.f;
      M[4]=s;  M[5]=0.f; M[6]=c;  M[7]=0.f;
    } else {             // RZ
      M[0]=c;  M[1]=-s;  M[2]=0.f; M[3]=0.f;
      M[4]=0.f; M[5]=0.f; M[6]=c;  M[7]=s;
    }
  }
  if (tid == 32) {
    float t1 = rx_theta[0]*0.5f, t2 = ry_theta[0]*0.5f;
    float c1=cosf(t1), s1=sinf(t1), c2=cosf(t2), s2=sinf(t2);
    float* M = gmats + NOPS * 8; // fused M = RY @ RX
    M[0]= c2*c1; M[1]= s2*s1;
    M[2]=-s2*c1; M[3]=-c2*s1;
    M[4]= s2*c1; M[5]=-c2*s1;
    M[6]= c2*c1; M[7]=-s2*s1;
  }

  if (tid < 32) {
    float acc = 0.f;
    for (int k = 0; k < 16; k++) acc += w3[k] * w2[k*32 + tid];
    r2[tid] = acc;
  }
  __syncthreads();
  {
    float acc = 0.f;
    for (int k = 0; k < 32; k++) acc += r2[k] * w1[k*64 + tid];
    r1[tid] = acc;
  }
  __syncthreads();
  if (tid < NW) {
    float acc = 0.f;
    for (int k = 0; k < 64; k++) acc += r1[k] * w0[k*NW + tid];
    weff[tid] = acc;
  }
  if (tid == NW) {
    float acc = b3[0];
    for (int k = 0; k < 16; k++) acc += w3[k] * b2[k];
    for (int k = 0; k < 32; k++) acc += r2[k] * b1[k];
    for (int k = 0; k < 64; k++) acc += r1[k] * b0[k];
    weff[NW] = acc;
  }
}

// ---------------------------------------------------------------------------
// Main sim kernel: one wave per batch element, 16 complex amps/lane in
// registers. flat = lane*16 + r; flat bit b<4 -> register bit (wire 9-b);
// b>=4 -> lane bit b-4 (wire 5-(b-4)).
// ---------------------------------------------------------------------------

#define APPLY1Q_REG(MK)                                                     \
  { _Pragma("unroll")                                                       \
    for (int r0 = 0; r0 < 16; r0++) {                                       \
      if (r0 & (MK)) continue;                                              \
      const int r1 = r0 | (MK);                                             \
      float a0r=re[r0], a0i=im[r0], a1r=re[r1], a1i=im[r1];                 \
      re[r0] = m00r*a0r - m00i*a0i + m01r*a1r - m01i*a1i;                   \
      im[r0] = m00r*a0i + m00i*a0r + m01r*a1i + m01i*a1r;                   \
      re[r1] = m10r*a0r - m10i*a0i + m11r*a1r - m11i*a1i;                   \
      im[r1] = m10r*a0i + m10i*a0r + m11r*a1i + m11i*a1r;                   \
    } }

#define CNOT_REG(MK)                                                        \
  { if (bc >= 4) {                                                          \
      const bool ctrl = ((lane >> (bc - 4)) & 1) != 0;                      \
      _Pragma("unroll")                                                     \
      for (int r0 = 0; r0 < 16; r0++) {                                     \
        if (r0 & (MK)) continue;                                            \
        const int r1 = r0 | (MK);                                           \
        float t0 = re[r0], t1v = re[r1];                                    \
        re[r0] = ctrl ? t1v : t0; re[r1] = ctrl ? t0 : t1v;                 \
        t0 = im[r0]; t1v = im[r1];                                          \
        im[r0] = ctrl ? t1v : t0; im[r1] = ctrl ? t0 : t1v;                 \
      }                                                                     \
    } else {                                                                \
      _Pragma("unroll")                                                     \
      for (int r0 = 0; r0 < 16; r0++) {                                     \
        if (r0 & (MK)) continue;                                            \
        const int r1 = r0 | (MK);                                           \
        const bool ctrl = ((r0 >> bc) & 1) != 0;                            \
        float t0 = re[r0], t1v = re[r1];                                    \
        re[r0] = ctrl ? t1v : t0; re[r1] = ctrl ? t0 : t1v;                 \
        t0 = im[r0]; t1v = im[r1];                                          \
        im[r0] = ctrl ? t1v : t0; im[r1] = ctrl ? t0 : t1v;                 \
      }                                                                     \
    } }

__global__ __launch_bounds__(256) void qsim_kernel(
    const float* __restrict__ x,
    const float* __restrict__ gmats,
    const float* __restrict__ weff,
    const float* __restrict__ head_w,
    const float* __restrict__ head_b,
    float* __restrict__ out,
    int bsz, Gates g)
{
  const int wv = (int)((blockIdx.x * blockDim.x + threadIdx.x) >> 6);
  const int lane = (int)(threadIdx.x & 63);
  if (wv >= bsz) return;
  const float* xe = x + wv * NW;

  float cw[NW], sw[NW];
#pragma unroll
  for (int w = 0; w < NW; w++) {
    float xv = xe[w] * 0.5f;
    cw[w] = __cosf(xv);
    sw[w] = __sinf(xv);
  }
  float pl = 1.0f;
#pragma unroll
  for (int lb = 0; lb < 6; lb++)
    pl *= ((lane >> lb) & 1) ? sw[5 - lb] : cw[5 - lb];

  float re[16], im[16];
#pragma unroll
  for (int r = 0; r < 16; r++) {
    float p = pl;
    p *= ((r >> 0) & 1) ? sw[9] : cw[9];
    p *= ((r >> 1) & 1) ? sw[8] : cw[8];
    p *= ((r >> 2) & 1) ? sw[7] : cw[7];
    p *= ((r >> 3) & 1) ? sw[6] : cw[6];
    re[r] = p; im[r] = 0.f;
  }

  for (int gi = 0; gi < g.n; gi++) {
    if (g.type[gi] == 0) {
      const float* M = gmats + g.slot[gi] * 8;
      const float m00r=M[0], m00i=M[1], m01r=M[2], m01i=M[3];
      const float m10r=M[4], m10i=M[5], m11r=M[6], m11i=M[7];
      const int bp = g.a[gi];
      if (bp >= 4) {
        const int lm = 1 << (bp - 4);
        const int bit = (lane >> (bp - 4)) & 1;
        const float car = bit ? m11r : m00r;
        const float cai = bit ? m11i : m00i;
        const float cbr = bit ? m10r : m01r;
        const float cbi = bit ? m10i : m01i;
#pragma unroll
        for (int r = 0; r < 16; r++) {
          float tr = __shfl_xor(re[r], lm);
          float ti = __shfl_xor(im[r], lm);
          float nr = car*re[r] - cai*im[r] + cbr*tr - cbi*ti;
          float ni = car*im[r] + cai*re[r] + cbr*ti + cbi*tr;
          re[r] = nr; im[r] = ni;
        }
      } else {
        switch (bp) {
          case 0:  APPLY1Q_REG(1); break;
          case 1:  APPLY1Q_REG(2); break;
          case 2:  APPLY1Q_REG(4); break;
          default: APPLY1Q_REG(8); break;
        }
      }
    } else {
      const int bc = g.a[gi], bt = g.b[gi];
      if (bt >= 4) {
        const int lm = 1 << (bt - 4);
        if (bc >= 4) {
          const bool ctrl = ((lane >> (bc - 4)) & 1) != 0;
#pragma unroll
          for (int r = 0; r < 16; r++) {
            float tr = __shfl_xor(re[r], lm);
            float ti = __shfl_xor(im[r], lm);
            re[r] = ctrl ? tr : re[r];
            im[r] = ctrl ? ti : im[r];
          }
        } else {
#pragma unroll
          for (int r = 0; r < 16; r++) {
            float tr = __shfl_xor(re[r], lm);
            float ti = __shfl_xor(im[r], lm);
            const bool ctrl = ((r >> bc) & 1) != 0;
            re[r] = ctrl ? tr : re[r];
            im[r] = ctrl ? ti : im[r];
          }
        }
      } else {
        switch (bt) {
          case 0:  CNOT_REG(1); break;
          case 1:  CNOT_REG(2); break;
          case 2:  CNOT_REG(4); break;
          default: CNOT_REG(8); break;
        }
      }
    }
  }

  float S = 0.f, z6 = 0.f, z7 = 0.f, z8 = 0.f, z9 = 0.f;
#pragma unroll
  for (int r = 0; r < 16; r++) {
    float p = re[r]*re[r] + im[r]*im[r];
    S += p;
    z9 += ((r >> 0) & 1) ? -p : p;
    z8 += ((r >> 1) & 1) ? -p : p;
    z7 += ((r >> 2) & 1) ? -p : p;
    z6 += ((r >> 3) & 1) ? -p : p;
  }
  float Z[10];
#pragma unroll
  for (int w = 0; w < 6; w++) {
    float v = ((lane >> (5 - w)) & 1) ? -S : S;
#pragma unroll
    for (int m = 1; m < 64; m <<= 1) v += __shfl_xor(v, m);
    Z[w] = v;
  }
  { float v = z6;
#pragma unroll
    for (int m = 1; m < 64; m <<= 1) v += __shfl_xor(v, m);
    Z[6] = v; }
  { float v = z7;
#pragma unroll
    for (int m = 1; m < 64; m <<= 1) v += __shfl_xor(v, m);
    Z[7] = v; }
  { float v = z8;
#pragma unroll
    for (int m = 1; m < 64; m <<= 1) v += __shfl_xor(v, m);
    Z[8] = v; }
  { float v = z9;
#pragma unroll
    for (int m = 1; m < 64; m <<= 1) v += __shfl_xor(v, m);
    Z[9] = v; }

  if (lane == 0) {
    float q = head_b[0];
#pragma unroll
    for (int w = 0; w < NW; w++) q += Z[w] * head_w[w];
    float cc = weff[NW];
#pragma unroll
    for (int w = 0; w < NW; w++) cc += xe[w] * weff[w];
    out[wv] = q + cc;
  }
}

// ---------------------------------------------------------------------------
// Host-side constexpr numpy RNG (SeedSequence + PCG64 XSL-RR 128/64).
// FIX vs R1-R5: SeedSequence mix() is MIX_MULT_L*x - MIX_MULT_R*y (SUB, not
// XOR). Compile-time certified against default_rng(42).random() x3.
// ---------------------------------------------------------------------------
namespace {

typedef unsigned __int128 u128;

struct CRng { u128 state; u128 inc; bool has32; uint32_t cached; };

constexpr u128 PCG_MUL = (((u128)0x2360ED051FC65DA4ULL) << 64) | (u128)0x4385DF649FCCF645ULL;

constexpr void cr_step(CRng &r) { r.state = r.state * PCG_MUL + r.inc; }

constexpr uint64_t cr_out(u128 st) {
  uint64_t hi = (uint64_t)(st >> 64);
  uint64_t lo = (uint64_t)st;
  unsigned rot = (unsigned)(st >> 122) & 63u;
  uint64_t v = hi ^ lo;
  return (v >> rot) | (v << ((64u - rot) & 63u));
}

// next_uint64 bypasses (does not consume/clear) the 32-bit half-word cache.
constexpr uint64_t cr_next64(CRng &r) { cr_step(r); return cr_out(r.state); }

constexpr uint32_t cr_next32(CRng &r) {
  if (r.has32) { r.has32 = false; return r.cached; }
  uint64_t v = cr_next64(r);
  r.has32 = true; r.cached = (uint32_t)(v >> 32);
  return (uint32_t)v;  // low half first, high half cached (pcg64_next32)
}

constexpr CRng cr_seed(uint32_t ent) {
  uint32_t pool[4] = {0u, 0u, 0u, 0u};
  uint32_t hc = 0x43b0d7e5u;              // INIT_A
  for (int i = 0; i < 4; i++) {           // hashmix entropy into pool
    uint32_t v = (i == 0) ? ent : 0u;
    v ^= hc; hc *= 0x931e8875u; v *= hc; v ^= v >> 16;
    pool[i] = v;
  }
  for (int s = 0; s < 4; s++)
    for (int d = 0; d < 4; d++)
      if (s != d) {
        uint32_t v = pool[s];
        v ^= hc; hc *= 0x931e8875u; v *= hc; v ^= v >> 16;        // hashmix
        uint32_t res = 0xca01f9ddu * pool[d] - 0x4973f715u * v;   // mix: SUB!
        res ^= res >> 16;
        pool[d] = res;
      }
  uint32_t hb = 0x8b51f9ddu;              // INIT_B
  uint64_t s64[4] = {0ull, 0ull, 0ull, 0ull};
  for (int i = 0; i < 8; i++) {           // generate_state(4, uint64)
    uint32_t d = pool[i & 3];
    d ^= hb; hb *= 0x58f38dedu; d *= hb; d ^= d >> 16;
    if (i & 1) s64[i >> 1] |= ((uint64_t)d << 32); else s64[i >> 1] = (uint64_t)d;
  }
  CRng r{};
  u128 initstate = (((u128)s64[0]) << 64) | (u128)s64[1];
  u128 initseq   = (((u128)s64[2]) << 64) | (u128)s64[3];
  r.state = 0; r.inc = (initseq << 1) | (u128)1;
  cr_step(r);
  r.state += initstate;
  cr_step(r);
  r.has32 = false; r.cached = 0u;
  return r;
}

// 32-bit Lemire in [0, rng] (numpy bounded_lemire_uint32). Every bounded draw
// in this problem routes here: random_bounded_uint64{,_fill} downshift to the
// 32-bit generator whenever rng <= 0xFFFFFFFF.
constexpr uint32_t cr_lemire32(CRng &r, uint32_t rng) {
  uint32_t rng_excl = rng + 1u;
  uint64_t m = (uint64_t)cr_next32(r) * (uint64_t)rng_excl;
  uint32_t leftover = (uint32_t)m;
  if (leftover < rng_excl) {
    uint32_t threshold = (uint32_t)(0xFFFFFFFFu - rng) % rng_excl;
    while (leftover < threshold) {
      m = (uint64_t)cr_next32(r) * (uint64_t)rng_excl;
      leftover = (uint32_t)m;
    }
  }
  return (uint32_t)(m >> 32);
}

// ---- COMPILE-TIME CANARY: default_rng(42).random() x3 -------------------
// numpy ground truth: 0.77395605, 0.43887844, 0.85859792
constexpr bool canary_pcg42() {
  CRng r = cr_seed(42u);
  double a = (double)(cr_next64(r) >> 11) * (1.0 / 9007199254740992.0);
  double b = (double)(cr_next64(r) >> 11) * (1.0 / 9007199254740992.0);
  double c = (double)(cr_next64(r) >> 11) * (1.0 / 9007199254740992.0);
  bool ok = (a > 0.77395603) && (a < 0.77395607);
  ok = ok && (b > 0.43887842) && (b < 0.43887846);
  ok = ok && (c > 0.85859790) && (c < 0.85859794);
  return ok;
}
static_assert(canary_pcg42(), "CANARY_PCG_SEED42_RANDOM_MISMATCH_pcg_or_seedseq_impl_bug");

} // namespace

extern "C" void kernel_launch(void* const* d_in, const int* in_sizes, int n_in,
                              void* d_out, int out_size, void* d_ws, size_t ws_size,
                              hipStream_t stream) {
  const float* x   = (const float*)d_in[0];
  const float* rp  = (const float*)d_in[1];
  const float* rxT = (const float*)d_in[2];
  const float* ryT = (const float*)d_in[3];
  const float* hw  = (const float*)d_in[4];
  const float* hb  = (const float*)d_in[5];
  const float* w0  = (const float*)d_in[6];
  const float* b0  = (const float*)d_in[7];
  const float* w1  = (const float*)d_in[8];
  const float* b1  = (const float*)d_in[9];
  const float* w2  = (const float*)d_in[10];
  const float* b2  = (const float*)d_in[11];
  const float* w3  = (const float*)d_in[12];
  const float* b3  = (const float*)d_in[13];
  const int bsz = in_sizes[0] / NW;

  // --- frozen 30-op circuit: all-32-bit-Lemire consumption model ---
  CRng rng = cr_seed(42u);
  int kinds[NOPS], wa[NOPS], wb[NOPS];
  for (int i = 0; i < NOPS; i++) {
    int k = (int)cr_lemire32(rng, 3u);        // integers(0,4)
    if (k == 3) {
      // choice(10,2,replace=False): Floyd, single-draw random_bounded_uint64
      // -> bounded_lemire_uint32 (rng <= 0xFFFFFFFF branch)
      uint32_t v8 = cr_lemire32(rng, 8u);     // j=8: [0,8]
      uint32_t v9 = cr_lemire32(rng, 9u);     // j=9: [0,9]
      uint32_t i0 = v8;
      uint32_t i1 = (v9 == v8) ? 9u : v9;     // hash-set dedup -> insert j
      // _shuffle_raw: i=1, j = random_bounded_uint64(0,1,0,0) -> lemire32(1)
      uint32_t j = cr_lemire32(rng, 1u);      // top bit of next uint32
      if (j == 0u) { uint32_t t = i0; i0 = i1; i1 = t; } // swap x[1]<->x[0]
      kinds[i] = 3; wa[i] = (int)i0; wb[i] = (int)i1;
    } else {
      int w = (int)cr_lemire32(rng, 9u);      // integers(0,10)
      kinds[i] = k; wa[i] = w; wb[i] = -1;
    }
  }

  // --- gate list (wire -> flat bit 9-wire) ---
  Gates g; g.n = 0;
  PrepInfo pi;
  for (int i = 0; i < NOPS; i++) {
    pi.kinds[i] = kinds[i];
    if (kinds[i] == 3) {
      g.type[g.n] = 1; g.a[g.n] = 9 - wa[i]; g.b[g.n] = 9 - wb[i]; g.slot[g.n] = 0; g.n++;
    } else {
      g.type[g.n] = 0; g.a[g.n] = 9 - wa[i]; g.b[g.n] = 0; g.slot[g.n] = i; g.n++;
    }
  }
  for (int w = 0; w < NW; w++) {
    g.type[g.n] = 0; g.a[g.n] = 9 - w; g.b[g.n] = 0; g.slot[g.n] = NOPS; g.n++;
  }

  float* gmats = (float*)d_ws;           // 31 slots * 8 floats
  float* weff  = gmats + (NOPS + 1) * 8; // W_eff[10] + b_eff

  hipLaunchKernelGGL(prep_kernel, dim3(1), dim3(64), 0, stream,
                     rp, rxT, ryT, w0, b0, w1, b1, w2, b2, w3, b3, gmats, weff, pi);

  const int blocks = (bsz + 3) / 4;
  hipLaunchKernelGGL(qsim_kernel, dim3(blocks), dim3(256), 0, stream,
                     x, gmats, weff, hw, hb, (float*)d_out, bsz, g);
}

// Round 7
// 137.922 us; speedup vs baseline: 1.2190x; 1.2190x over previous
//
#include <hip/hip_runtime.h>
#include <cstdint>

#define NW 10
#define NOPS 30
#define MAXG 48

// ---------------------------------------------------------------------------
// Constexpr numpy RNG (SeedSequence + PCG64 XSL-RR), canary-certified.
// The circuit is built at COMPILE TIME and baked into the kernel.
// ---------------------------------------------------------------------------
namespace {

typedef unsigned __int128 u128;

struct CRng { u128 state; u128 inc; bool has32; uint32_t cached; };

constexpr u128 PCG_MUL = (((u128)0x2360ED051FC65DA4ULL) << 64) | (u128)0x4385DF649FCCF645ULL;

constexpr void cr_step(CRng &r) { r.state = r.state * PCG_MUL + r.inc; }

constexpr uint64_t cr_out(u128 st) {
  uint64_t hi = (uint64_t)(st >> 64);
  uint64_t lo = (uint64_t)st;
  unsigned rot = (unsigned)(st >> 122) & 63u;
  uint64_t v = hi ^ lo;
  return (v >> rot) | (v << ((64u - rot) & 63u));
}

constexpr uint64_t cr_next64(CRng &r) { cr_step(r); return cr_out(r.state); }

constexpr uint32_t cr_next32(CRng &r) {
  if (r.has32) { r.has32 = false; return r.cached; }
  uint64_t v = cr_next64(r);
  r.has32 = true; r.cached = (uint32_t)(v >> 32);
  return (uint32_t)v;
}

constexpr CRng cr_seed(uint32_t ent) {
  uint32_t pool[4] = {0u, 0u, 0u, 0u};
  uint32_t hc = 0x43b0d7e5u;              // INIT_A
  for (int i = 0; i < 4; i++) {
    uint32_t v = (i == 0) ? ent : 0u;
    v ^= hc; hc *= 0x931e8875u; v *= hc; v ^= v >> 16;
    pool[i] = v;
  }
  for (int s = 0; s < 4; s++)
    for (int d = 0; d < 4; d++)
      if (s != d) {
        uint32_t v = pool[s];
        v ^= hc; hc *= 0x931e8875u; v *= hc; v ^= v >> 16;        // hashmix
        uint32_t res = 0xca01f9ddu * pool[d] - 0x4973f715u * v;   // mix (SUB)
        res ^= res >> 16;
        pool[d] = res;
      }
  uint32_t hb = 0x8b51f9ddu;              // INIT_B
  uint64_t s64[4] = {0ull, 0ull, 0ull, 0ull};
  for (int i = 0; i < 8; i++) {
    uint32_t d = pool[i & 3];
    d ^= hb; hb *= 0x58f38dedu; d *= hb; d ^= d >> 16;
    if (i & 1) s64[i >> 1] |= ((uint64_t)d << 32); else s64[i >> 1] = (uint64_t)d;
  }
  CRng r{};
  u128 initstate = (((u128)s64[0]) << 64) | (u128)s64[1];
  u128 initseq   = (((u128)s64[2]) << 64) | (u128)s64[3];
  r.state = 0; r.inc = (initseq << 1) | (u128)1;
  cr_step(r);
  r.state += initstate;
  cr_step(r);
  r.has32 = false; r.cached = 0u;
  return r;
}

constexpr uint32_t cr_lemire32(CRng &r, uint32_t rng) {
  uint32_t rng_excl = rng + 1u;
  uint64_t m = (uint64_t)cr_next32(r) * (uint64_t)rng_excl;
  uint32_t leftover = (uint32_t)m;
  if (leftover < rng_excl) {
    uint32_t threshold = (uint32_t)(0xFFFFFFFFu - rng) % rng_excl;
    while (leftover < threshold) {
      m = (uint64_t)cr_next32(r) * (uint64_t)rng_excl;
      leftover = (uint32_t)m;
    }
  }
  return (uint32_t)(m >> 32);
}

constexpr bool canary_pcg42() {
  CRng r = cr_seed(42u);
  double a = (double)(cr_next64(r) >> 11) * (1.0 / 9007199254740992.0);
  double b = (double)(cr_next64(r) >> 11) * (1.0 / 9007199254740992.0);
  double c = (double)(cr_next64(r) >> 11) * (1.0 / 9007199254740992.0);
  bool ok = (a > 0.77395603) && (a < 0.77395607);
  ok = ok && (b > 0.43887842) && (b < 0.43887846);
  ok = ok && (c > 0.85859790) && (c < 0.85859794);
  return ok;
}
static_assert(canary_pcg42(), "CANARY_PCG_SEED42_RANDOM_MISMATCH");

// ---- compile-time circuit -------------------------------------------------
// kind: 0 RX, 1 RY, 2 RZ, 3 CNOT (ba=control bit, bb=target bit), 4 fused tail
// bit = 9 - wire; bit<4 -> register bit; bit>=4 -> lane bit (bit-4).
struct COp { int kind; int ba; int bb; int slot; };
struct Circ { COp op[MAXG]; int n; int kind_by_op[NOPS]; };

constexpr Circ build_circuit() {
  Circ c{};
  c.n = 0;
  for (int i = 0; i < NOPS; i++) c.kind_by_op[i] = 3;
  CRng r = cr_seed(42u);
  for (int i = 0; i < NOPS; i++) {
    int k = (int)cr_lemire32(r, 3u);            // integers(0,4)
    if (k == 3) {
      uint32_t v8 = cr_lemire32(r, 8u);         // Floyd j=8
      uint32_t v9 = cr_lemire32(r, 9u);         // Floyd j=9
      uint32_t i0 = v8;
      uint32_t i1 = (v9 == v8) ? 9u : v9;
      uint32_t j = cr_lemire32(r, 1u);          // shuffle swap bit
      if (j == 0u) { uint32_t t = i0; i0 = i1; i1 = t; }
      c.kind_by_op[i] = 3;
      c.op[c.n] = COp{3, 9 - (int)i0, 9 - (int)i1, 0}; c.n++;
    } else {
      int w = (int)cr_lemire32(r, 9u);          // integers(0,10)
      c.kind_by_op[i] = k;
      c.op[c.n] = COp{k, 9 - w, 0, i}; c.n++;
    }
  }
  return c; // tail (10 fused gates) handled separately in qsim
}
constexpr Circ CC = build_circuit();
constexpr int NRAND = CC.n;

} // namespace

// ---------------------------------------------------------------------------
// Prep kernel: (c,s) per 1q op -> ws[0..59]; fused M=RY@RX -> ws[64..71];
// collapsed linear MLP W_eff[10],b_eff -> ws[80..90].
// ---------------------------------------------------------------------------
__global__ __launch_bounds__(64) void prep_kernel(
    const float* __restrict__ rand_params,
    const float* __restrict__ rx_theta, const float* __restrict__ ry_theta,
    const float* __restrict__ w0, const float* __restrict__ b0,
    const float* __restrict__ w1, const float* __restrict__ b1,
    const float* __restrict__ w2, const float* __restrict__ b2,
    const float* __restrict__ w3, const float* __restrict__ b3,
    float* __restrict__ ws)
{
  const int tid = threadIdx.x;
  __shared__ float r2[32];
  __shared__ float r1[64];

  if (tid < NOPS && CC.kind_by_op[tid] < 3) {
    float t = rand_params[tid] * 0.5f;
    ws[2*tid]   = cosf(t);
    ws[2*tid+1] = sinf(t);
  }
  if (tid == 32) {
    // Fused M = RY(ry) @ RX(rx)  (RX applied first)
    float t1 = rx_theta[0]*0.5f, t2 = ry_theta[0]*0.5f;
    float c1=cosf(t1), s1=sinf(t1), c2=cosf(t2), s2=sinf(t2);
    float* M = ws + 64;
    M[0]= c2*c1; M[1]= s2*s1;
    M[2]=-s2*c1; M[3]=-c2*s1;
    M[4]= s2*c1; M[5]=-c2*s1;
    M[6]= c2*c1; M[7]=-s2*s1;
  }

  // MLP collapse (no activations -> fully linear)
  if (tid < 32) {
    float acc = 0.f;
    for (int k = 0; k < 16; k++) acc += w3[k] * w2[k*32 + tid];
    r2[tid] = acc;
  }
  __syncthreads();
  {
    float acc = 0.f;
    for (int k = 0; k < 32; k++) acc += r2[k] * w1[k*64 + tid];
    r1[tid] = acc;
  }
  __syncthreads();
  if (tid < NW) {
    float acc = 0.f;
    for (int k = 0; k < 64; k++) acc += r1[k] * w0[k*NW + tid];
    ws[80 + tid] = acc;
  }
  if (tid == NW) {
    float acc = b3[0];
    for (int k = 0; k < 16; k++) acc += w3[k] * b2[k];
    for (int k = 0; k < 32; k++) acc += r2[k] * b1[k];
    for (int k = 0; k < 64; k++) acc += r1[k] * b0[k];
    ws[80 + NW] = acc;
  }
}

// ---------------------------------------------------------------------------
// Fully-unrolled compile-time gate chain, specialized per gate kind.
// ---------------------------------------------------------------------------
template<int GI>
__device__ __forceinline__ void apply_rand(float (&re)[16], float (&im)[16],
                                           const float* __restrict__ ws,
                                           const int lane)
{
  if constexpr (GI < NRAND) {
    constexpr COp G = CC.op[GI];

    if constexpr (G.kind == 3) {
      // ---- CNOT: control G.ba, target G.bb ----
      if constexpr (G.bb < 4) {
        constexpr int MK = 1 << G.bb;
        if constexpr (G.ba < 4) {
          // reg control, reg target: compile-time register swap (free)
#pragma unroll
          for (int r0 = 0; r0 < 16; r0++)
            if (!(r0 & MK) && ((r0 >> G.ba) & 1)) {
              const int r1 = r0 | MK;
              float t = re[r0]; re[r0] = re[r1]; re[r1] = t;
              t = im[r0]; im[r0] = im[r1]; im[r1] = t;
            }
        } else {
          const bool ctrl = ((lane >> (G.ba - 4)) & 1) != 0;
#pragma unroll
          for (int r0 = 0; r0 < 16; r0++)
            if (!(r0 & MK)) {
              const int r1 = r0 | MK;
              float t0 = re[r0], t1 = re[r1];
              re[r0] = ctrl ? t1 : t0; re[r1] = ctrl ? t0 : t1;
              t0 = im[r0]; t1 = im[r1];
              im[r0] = ctrl ? t1 : t0; im[r1] = ctrl ? t0 : t1;
            }
        }
      } else {
        constexpr int LM = 1 << (G.bb - 4);
        if constexpr (G.ba < 4) {
          // reg control, lane target: exchange only ctrl=1 regs, no selects
#pragma unroll
          for (int r = 0; r < 16; r++)
            if ((r >> G.ba) & 1) {
              re[r] = __shfl_xor(re[r], LM);
              im[r] = __shfl_xor(im[r], LM);
            }
        } else {
          const bool ctrl = ((lane >> (G.ba - 4)) & 1) != 0;
#pragma unroll
          for (int r = 0; r < 16; r++) {
            float pr = __shfl_xor(re[r], LM);
            float pi = __shfl_xor(im[r], LM);
            re[r] = ctrl ? pr : re[r];
            im[r] = ctrl ? pi : im[r];
          }
        }
      }
    } else {
      const float c = ws[2*G.slot];
      const float s = ws[2*G.slot + 1];
      if constexpr (G.kind == 0) {
        // ---- RX: [[c,-is],[-is,c]] ----
        if constexpr (G.ba < 4) {
          constexpr int MK = 1 << G.ba;
#pragma unroll
          for (int r0 = 0; r0 < 16; r0++)
            if (!(r0 & MK)) {
              const int r1 = r0 | MK;
              float a0r=re[r0], a0i=im[r0], a1r=re[r1], a1i=im[r1];
              re[r0] = fmaf(s, a1i, c*a0r);
              im[r0] = fmaf(-s, a1r, c*a0i);
              re[r1] = fmaf(s, a0i, c*a1r);
              im[r1] = fmaf(-s, a0r, c*a1i);
            }
        } else {
          constexpr int LM = 1 << (G.ba - 4);
#pragma unroll
          for (int r = 0; r < 16; r++) {
            float pr = __shfl_xor(re[r], LM);
            float pi = __shfl_xor(im[r], LM);
            re[r] = fmaf(s, pi, c*re[r]);
            im[r] = fmaf(-s, pr, c*im[r]);
          }
        }
      } else if constexpr (G.kind == 1) {
        // ---- RY: [[c,-s],[s,c]] (all real) ----
        if constexpr (G.ba < 4) {
          constexpr int MK = 1 << G.ba;
#pragma unroll
          for (int r0 = 0; r0 < 16; r0++)
            if (!(r0 & MK)) {
              const int r1 = r0 | MK;
              float a0r=re[r0], a0i=im[r0], a1r=re[r1], a1i=im[r1];
              re[r0] = fmaf(-s, a1r, c*a0r);
              im[r0] = fmaf(-s, a1i, c*a0i);
              re[r1] = fmaf(s, a0r, c*a1r);
              im[r1] = fmaf(s, a0i, c*a1i);
            }
        } else {
          constexpr int LM = 1 << (G.ba - 4);
          const float sg = ((lane >> (G.ba - 4)) & 1) ? s : -s;
#pragma unroll
          for (int r = 0; r < 16; r++) {
            float pr = __shfl_xor(re[r], LM);
            float pi = __shfl_xor(im[r], LM);
            re[r] = fmaf(sg, pr, c*re[r]);
            im[r] = fmaf(sg, pi, c*im[r]);
          }
        }
      } else {
        // ---- RZ: diag(c-is, c+is) — diagonal, NO shuffles ever ----
        if constexpr (G.ba < 4) {
#pragma unroll
          for (int r = 0; r < 16; r++) {
            const float u = ((r >> G.ba) & 1) ? -s : s;
            float rr = re[r], ii = im[r];
            re[r] = fmaf(u, ii, c*rr);
            im[r] = fmaf(-u, rr, c*ii);
          }
        } else {
          const float u = ((lane >> (G.ba - 4)) & 1) ? -s : s;
#pragma unroll
          for (int r = 0; r < 16; r++) {
            float rr = re[r], ii = im[r];
            re[r] = fmaf(u, ii, c*rr);
            im[r] = fmaf(-u, rr, c*ii);
          }
        }
      }
    }
    apply_rand<GI + 1>(re, im, ws, lane);
  }
}

// Fused tail gate (dense complex 2x2), bit position B compile-time.
template<int B>
__device__ __forceinline__ void apply_fused(float (&re)[16], float (&im)[16],
                                            const float m00r, const float m00i,
                                            const float m01r, const float m01i,
                                            const float m10r, const float m10i,
                                            const float m11r, const float m11i,
                                            const int lane)
{
  if constexpr (B < 4) {
    constexpr int MK = 1 << B;
#pragma unroll
    for (int r0 = 0; r0 < 16; r0++)
      if (!(r0 & MK)) {
        const int r1 = r0 | MK;
        float a0r=re[r0], a0i=im[r0], a1r=re[r1], a1i=im[r1];
        re[r0] = m00r*a0r - m00i*a0i + m01r*a1r - m01i*a1i;
        im[r0] = m00r*a0i + m00i*a0r + m01r*a1i + m01i*a1r;
        re[r1] = m10r*a0r - m10i*a0i + m11r*a1r - m11i*a1i;
        im[r1] = m10r*a0i + m10i*a0r + m11r*a1i + m11i*a1r;
      }
  } else {
    constexpr int LM = 1 << (B - 4);
    const int bit = (lane >> (B - 4)) & 1;
    const float car = bit ? m11r : m00r;
    const float cai = bit ? m11i : m00i;
    const float cbr = bit ? m10r : m01r;
    const float cbi = bit ? m10i : m01i;
#pragma unroll
    for (int r = 0; r < 16; r++) {
      float pr = __shfl_xor(re[r], LM);
      float pi = __shfl_xor(im[r], LM);
      float nr = car*re[r] - cai*im[r] + cbr*pr - cbi*pi;
      float ni = car*im[r] + cai*re[r] + cbr*pi + cbi*pr;
      re[r] = nr; im[r] = ni;
    }
  }
}

// ---------------------------------------------------------------------------
// Main sim kernel: one wave per batch element, 16 complex amps/lane.
// flat = lane*16 + r; flat bit b<4 -> reg bit; b>=4 -> lane bit b-4.
// wire w <-> flat bit 9-w.
// ---------------------------------------------------------------------------
__global__ __launch_bounds__(256) void qsim_kernel(
    const float* __restrict__ x,
    const float* __restrict__ ws,
    const float* __restrict__ head_w,
    const float* __restrict__ head_b,
    float* __restrict__ out,
    int bsz)
{
  const int wv = (int)((blockIdx.x * blockDim.x + threadIdx.x) >> 6);
  const int lane = (int)(threadIdx.x & 63);
  if (wv >= bsz) return;
  const float* xe = x + wv * NW;

  // ---- Encoder: product state from RY(x_w)|0> ----
  float cw[NW], sw[NW];
#pragma unroll
  for (int w = 0; w < NW; w++) {
    float xv = xe[w] * 0.5f;
    cw[w] = __cosf(xv);
    sw[w] = __sinf(xv);
  }
  float pl = 1.0f;
#pragma unroll
  for (int lb = 0; lb < 6; lb++)      // lane bit lb <-> wire 5-lb
    pl *= ((lane >> lb) & 1) ? sw[5 - lb] : cw[5 - lb];

  float re[16], im[16];
#pragma unroll
  for (int r = 0; r < 16; r++) {      // reg bit rb <-> wire 9-rb
    float p = pl;
    p *= ((r >> 0) & 1) ? sw[9] : cw[9];
    p *= ((r >> 1) & 1) ? sw[8] : cw[8];
    p *= ((r >> 2) & 1) ? sw[7] : cw[7];
    p *= ((r >> 3) & 1) ? sw[6] : cw[6];
    re[r] = p; im[r] = 0.f;
  }

  // ---- Random section (compile-time unrolled, specialized) ----
  apply_rand<0>(re, im, ws, lane);

  // ---- Fused tail: M = RY@RX on every wire (load M once) ----
  {
    const float m00r = ws[64], m00i = ws[65], m01r = ws[66], m01i = ws[67];
    const float m10r = ws[68], m10i = ws[69], m11r = ws[70], m11i = ws[71];
    apply_fused<0>(re, im, m00r,m00i,m01r,m01i,m10r,m10i,m11r,m11i, lane);
    apply_fused<1>(re, im, m00r,m00i,m01r,m01i,m10r,m10i,m11r,m11i, lane);
    apply_fused<2>(re, im, m00r,m00i,m01r,m01i,m10r,m10i,m11r,m11i, lane);
    apply_fused<3>(re, im, m00r,m00i,m01r,m01i,m10r,m10i,m11r,m11i, lane);
    apply_fused<4>(re, im, m00r,m00i,m01r,m01i,m10r,m10i,m11r,m11i, lane);
    apply_fused<5>(re, im, m00r,m00i,m01r,m01i,m10r,m10i,m11r,m11i, lane);
    apply_fused<6>(re, im, m00r,m00i,m01r,m01i,m10r,m10i,m11r,m11i, lane);
    apply_fused<7>(re, im, m00r,m00i,m01r,m01i,m10r,m10i,m11r,m11i, lane);
    apply_fused<8>(re, im, m00r,m00i,m01r,m01i,m10r,m10i,m11r,m11i, lane);
    apply_fused<9>(re, im, m00r,m00i,m01r,m01i,m10r,m10i,m11r,m11i, lane);
  }

  // ---- MeasureAll(Z) ----
  float S = 0.f, z6 = 0.f, z7 = 0.f, z8 = 0.f, z9 = 0.f;
#pragma unroll
  for (int r = 0; r < 16; r++) {
    float p = re[r]*re[r] + im[r]*im[r];
    S += p;
    z9 += ((r >> 0) & 1) ? -p : p;
    z8 += ((r >> 1) & 1) ? -p : p;
    z7 += ((r >> 2) & 1) ? -p : p;
    z6 += ((r >> 3) & 1) ? -p : p;
  }
  float Z[10];
#pragma unroll
  for (int w = 0; w < 6; w++) {       // wire w (0..5) <-> lane bit 5-w
    float v = ((lane >> (5 - w)) & 1) ? -S : S;
#pragma unroll
    for (int m = 1; m < 64; m <<= 1) v += __shfl_xor(v, m);
    Z[w] = v;
  }
  { float v = z6;
#pragma unroll
    for (int m = 1; m < 64; m <<= 1) v += __shfl_xor(v, m);
    Z[6] = v; }
  { float v = z7;
#pragma unroll
    for (int m = 1; m < 64; m <<= 1) v += __shfl_xor(v, m);
    Z[7] = v; }
  { float v = z8;
#pragma unroll
    for (int m = 1; m < 64; m <<= 1) v += __shfl_xor(v, m);
    Z[8] = v; }
  { float v = z9;
#pragma unroll
    for (int m = 1; m < 64; m <<= 1) v += __shfl_xor(v, m);
    Z[9] = v; }

  if (lane == 0) {
    float q = head_b[0];
#pragma unroll
    for (int w = 0; w < NW; w++) q += Z[w] * head_w[w];
    float cc = ws[80 + NW];
#pragma unroll
    for (int w = 0; w < NW; w++) cc += xe[w] * ws[80 + w];
    out[wv] = q + cc;
  }
}

extern "C" void kernel_launch(void* const* d_in, const int* in_sizes, int n_in,
                              void* d_out, int out_size, void* d_ws, size_t ws_size,
                              hipStream_t stream) {
  const float* x   = (const float*)d_in[0];
  const float* rp  = (const float*)d_in[1];
  const float* rxT = (const float*)d_in[2];
  const float* ryT = (const float*)d_in[3];
  const float* hw  = (const float*)d_in[4];
  const float* hb  = (const float*)d_in[5];
  const float* w0  = (const float*)d_in[6];
  const float* b0  = (const float*)d_in[7];
  const float* w1  = (const float*)d_in[8];
  const float* b1  = (const float*)d_in[9];
  const float* w2  = (const float*)d_in[10];
  const float* b2  = (const float*)d_in[11];
  const float* w3  = (const float*)d_in[12];
  const float* b3  = (const float*)d_in[13];
  const int bsz = in_sizes[0] / NW;

  float* ws = (float*)d_ws;

  hipLaunchKernelGGL(prep_kernel, dim3(1), dim3(64), 0, stream,
                     rp, rxT, ryT, w0, b0, w1, b1, w2, b2, w3, b3, ws);

  const int blocks = (bsz + 3) / 4; // 4 waves per 256-thread block
  hipLaunchKernelGGL(qsim_kernel, dim3(blocks), dim3(256), 0, stream,
                     x, ws, hw, hb, (float*)d_out, bsz);
}

// Round 8
// 132.779 us; speedup vs baseline: 1.2662x; 1.0387x over previous
//
#include <hip/hip_runtime.h>
#include <cstdint>

#define NW 10
#define NOPS 30
#define MAXG 48

typedef float v2f __attribute__((ext_vector_type(2)));

// ---------------------------------------------------------------------------
// Constexpr numpy RNG (SeedSequence + PCG64 XSL-RR), canary-certified.
// Circuit baked at compile time.
// ---------------------------------------------------------------------------
namespace {

typedef unsigned __int128 u128;

struct CRng { u128 state; u128 inc; bool has32; uint32_t cached; };

constexpr u128 PCG_MUL = (((u128)0x2360ED051FC65DA4ULL) << 64) | (u128)0x4385DF649FCCF645ULL;

constexpr void cr_step(CRng &r) { r.state = r.state * PCG_MUL + r.inc; }

constexpr uint64_t cr_out(u128 st) {
  uint64_t hi = (uint64_t)(st >> 64);
  uint64_t lo = (uint64_t)st;
  unsigned rot = (unsigned)(st >> 122) & 63u;
  uint64_t v = hi ^ lo;
  return (v >> rot) | (v << ((64u - rot) & 63u));
}

constexpr uint64_t cr_next64(CRng &r) { cr_step(r); return cr_out(r.state); }

constexpr uint32_t cr_next32(CRng &r) {
  if (r.has32) { r.has32 = false; return r.cached; }
  uint64_t v = cr_next64(r);
  r.has32 = true; r.cached = (uint32_t)(v >> 32);
  return (uint32_t)v;
}

constexpr CRng cr_seed(uint32_t ent) {
  uint32_t pool[4] = {0u, 0u, 0u, 0u};
  uint32_t hc = 0x43b0d7e5u;              // INIT_A
  for (int i = 0; i < 4; i++) {
    uint32_t v = (i == 0) ? ent : 0u;
    v ^= hc; hc *= 0x931e8875u; v *= hc; v ^= v >> 16;
    pool[i] = v;
  }
  for (int s = 0; s < 4; s++)
    for (int d = 0; d < 4; d++)
      if (s != d) {
        uint32_t v = pool[s];
        v ^= hc; hc *= 0x931e8875u; v *= hc; v ^= v >> 16;        // hashmix
        uint32_t res = 0xca01f9ddu * pool[d] - 0x4973f715u * v;   // mix (SUB)
        res ^= res >> 16;
        pool[d] = res;
      }
  uint32_t hb = 0x8b51f9ddu;              // INIT_B
  uint64_t s64[4] = {0ull, 0ull, 0ull, 0ull};
  for (int i = 0; i < 8; i++) {
    uint32_t d = pool[i & 3];
    d ^= hb; hb *= 0x58f38dedu; d *= hb; d ^= d >> 16;
    if (i & 1) s64[i >> 1] |= ((uint64_t)d << 32); else s64[i >> 1] = (uint64_t)d;
  }
  CRng r{};
  u128 initstate = (((u128)s64[0]) << 64) | (u128)s64[1];
  u128 initseq   = (((u128)s64[2]) << 64) | (u128)s64[3];
  r.state = 0; r.inc = (initseq << 1) | (u128)1;
  cr_step(r);
  r.state += initstate;
  cr_step(r);
  r.has32 = false; r.cached = 0u;
  return r;
}

constexpr uint32_t cr_lemire32(CRng &r, uint32_t rng) {
  uint32_t rng_excl = rng + 1u;
  uint64_t m = (uint64_t)cr_next32(r) * (uint64_t)rng_excl;
  uint32_t leftover = (uint32_t)m;
  if (leftover < rng_excl) {
    uint32_t threshold = (uint32_t)(0xFFFFFFFFu - rng) % rng_excl;
    while (leftover < threshold) {
      m = (uint64_t)cr_next32(r) * (uint64_t)rng_excl;
      leftover = (uint32_t)m;
    }
  }
  return (uint32_t)(m >> 32);
}

constexpr bool canary_pcg42() {
  CRng r = cr_seed(42u);
  double a = (double)(cr_next64(r) >> 11) * (1.0 / 9007199254740992.0);
  double b = (double)(cr_next64(r) >> 11) * (1.0 / 9007199254740992.0);
  double c = (double)(cr_next64(r) >> 11) * (1.0 / 9007199254740992.0);
  bool ok = (a > 0.77395603) && (a < 0.77395607);
  ok = ok && (b > 0.43887842) && (b < 0.43887846);
  ok = ok && (c > 0.85859790) && (c < 0.85859794);
  return ok;
}
static_assert(canary_pcg42(), "CANARY_PCG_SEED42_RANDOM_MISMATCH");

// ---- compile-time circuit -------------------------------------------------
// kind: 0 RX, 1 RY, 2 RZ, 3 CNOT (ba=control bit, bb=target bit)
// bit = 9 - wire; bit<4 -> register bit; bit>=4 -> lane bit (bit-4).
struct COp { int kind; int ba; int bb; int slot; };
struct Circ { COp op[MAXG]; int n; int kind_by_op[NOPS]; };

constexpr Circ build_circuit() {
  Circ c{};
  c.n = 0;
  for (int i = 0; i < NOPS; i++) c.kind_by_op[i] = 3;
  CRng r = cr_seed(42u);
  for (int i = 0; i < NOPS; i++) {
    int k = (int)cr_lemire32(r, 3u);            // integers(0,4)
    if (k == 3) {
      uint32_t v8 = cr_lemire32(r, 8u);         // Floyd j=8
      uint32_t v9 = cr_lemire32(r, 9u);         // Floyd j=9
      uint32_t i0 = v8;
      uint32_t i1 = (v9 == v8) ? 9u : v9;
      uint32_t j = cr_lemire32(r, 1u);          // shuffle swap bit
      if (j == 0u) { uint32_t t = i0; i0 = i1; i1 = t; }
      c.kind_by_op[i] = 3;
      c.op[c.n] = COp{3, 9 - (int)i0, 9 - (int)i1, 0}; c.n++;
    } else {
      int w = (int)cr_lemire32(r, 9u);          // integers(0,10)
      c.kind_by_op[i] = k;
      c.op[c.n] = COp{k, 9 - w, 0, i}; c.n++;
    }
  }
  return c;
}
constexpr Circ CC = build_circuit();
constexpr int NRAND = CC.n;

} // namespace

// ---------------------------------------------------------------------------
// Prep kernel: (c,s) per 1q op -> ws[0..59]; O = M^T Z M params (a,br,bi)
// -> ws[72..74]; collapsed linear MLP W_eff[10],b_eff -> ws[80..90].
// ---------------------------------------------------------------------------
__global__ __launch_bounds__(64) void prep_kernel(
    const float* __restrict__ rand_params,
    const float* __restrict__ rx_theta, const float* __restrict__ ry_theta,
    const float* __restrict__ w0, const float* __restrict__ b0,
    const float* __restrict__ w1, const float* __restrict__ b1,
    const float* __restrict__ w2, const float* __restrict__ b2,
    const float* __restrict__ w3, const float* __restrict__ b3,
    float* __restrict__ ws)
{
  const int tid = threadIdx.x;
  __shared__ float r2[32];
  __shared__ float r1[64];

  if (tid < NOPS && CC.kind_by_op[tid] < 3) {
    float t = rand_params[tid] * 0.5f;
    ws[2*tid]   = cosf(t);
    ws[2*tid+1] = sinf(t);
  }
  if (tid == 33) {
    // O = M^dag Z M for M = RY(ty) @ RX(tx):
    // a = cos(tx) cos(ty); b = -sin(ty) - i sin(tx) cos(ty)
    float tx = rx_theta[0], ty = ry_theta[0];
    float cx = cosf(tx), sx = sinf(tx), cy = cosf(ty), sy = sinf(ty);
    ws[72] = cx * cy;       // a
    ws[73] = -sy;           // br
    ws[74] = -sx * cy;      // bi
  }

  // MLP collapse (no activations -> fully linear)
  if (tid < 32) {
    float acc = 0.f;
    for (int k = 0; k < 16; k++) acc += w3[k] * w2[k*32 + tid];
    r2[tid] = acc;
  }
  __syncthreads();
  {
    float acc = 0.f;
    for (int k = 0; k < 32; k++) acc += r2[k] * w1[k*64 + tid];
    r1[tid] = acc;
  }
  __syncthreads();
  if (tid < NW) {
    float acc = 0.f;
    for (int k = 0; k < 64; k++) acc += r1[k] * w0[k*NW + tid];
    ws[80 + tid] = acc;
  }
  if (tid == NW) {
    float acc = b3[0];
    for (int k = 0; k < 16; k++) acc += w3[k] * b2[k];
    for (int k = 0; k < 32; k++) acc += r2[k] * b1[k];
    for (int k = 0; k < 64; k++) acc += r1[k] * b0[k];
    ws[80 + NW] = acc;
  }
}

// ---------------------------------------------------------------------------
// Packed helpers. A = (re, im). jmul(A) = -i*psi representation: (im, -re).
// ---------------------------------------------------------------------------
__device__ __forceinline__ v2f jmul(v2f v) { return (v2f){v.y, -v.x}; }

__device__ __forceinline__ v2f shfl2(v2f v, int m) {
  v2f r;
  r.x = __shfl_xor(v.x, m);
  r.y = __shfl_xor(v.y, m);
  return r;
}

// ---------------------------------------------------------------------------
// Fully-unrolled compile-time gate chain over packed amplitudes A[16].
// ---------------------------------------------------------------------------
template<int GI>
__device__ __forceinline__ void apply_rand(v2f (&A)[16],
                                           const float* __restrict__ ws,
                                           const int lane)
{
  if constexpr (GI < NRAND) {
    constexpr COp G = CC.op[GI];

    if constexpr (G.kind == 3) {
      // ---- CNOT ----
      if constexpr (G.bb < 4) {
        constexpr int MK = 1 << G.bb;
        if constexpr (G.ba < 4) {
          // reg control, reg target: compile-time register swap (free)
#pragma unroll
          for (int r0 = 0; r0 < 16; r0++)
            if (!(r0 & MK) && ((r0 >> G.ba) & 1)) {
              const int r1 = r0 | MK;
              v2f t = A[r0]; A[r0] = A[r1]; A[r1] = t;
            }
        } else {
          const bool ctrl = ((lane >> (G.ba - 4)) & 1) != 0;
#pragma unroll
          for (int r0 = 0; r0 < 16; r0++)
            if (!(r0 & MK)) {
              const int r1 = r0 | MK;
              v2f t0 = A[r0], t1 = A[r1];
              A[r0] = ctrl ? t1 : t0;
              A[r1] = ctrl ? t0 : t1;
            }
        }
      } else {
        constexpr int LM = 1 << (G.bb - 4);
        if constexpr (G.ba < 4) {
          // reg control, lane target: exchange ctrl=1 regs only
#pragma unroll
          for (int r = 0; r < 16; r++)
            if ((r >> G.ba) & 1) A[r] = shfl2(A[r], LM);
        } else {
          const bool ctrl = ((lane >> (G.ba - 4)) & 1) != 0;
#pragma unroll
          for (int r = 0; r < 16; r++) {
            v2f p = shfl2(A[r], LM);
            A[r] = ctrl ? p : A[r];
          }
        }
      }
    } else {
      const float c = ws[2*G.slot];
      const float s = ws[2*G.slot + 1];
      if constexpr (G.kind == 0) {
        // ---- RX: psi0' = c psi0 - i s psi1 ; psi1' = -i s psi0 + c psi1 ----
        if constexpr (G.ba < 4) {
          constexpr int MK = 1 << G.ba;
#pragma unroll
          for (int r0 = 0; r0 < 16; r0++)
            if (!(r0 & MK)) {
              const int r1 = r0 | MK;
              v2f a0 = A[r0], a1 = A[r1];
              A[r0] = c*a0 + s*jmul(a1);
              A[r1] = c*a1 + s*jmul(a0);
            }
        } else {
          constexpr int LM = 1 << (G.ba - 4);
#pragma unroll
          for (int r = 0; r < 16; r++) {
            v2f p = shfl2(A[r], LM);
            A[r] = c*A[r] + s*jmul(p);
          }
        }
      } else if constexpr (G.kind == 1) {
        // ---- RY (all real) ----
        if constexpr (G.ba < 4) {
          constexpr int MK = 1 << G.ba;
#pragma unroll
          for (int r0 = 0; r0 < 16; r0++)
            if (!(r0 & MK)) {
              const int r1 = r0 | MK;
              v2f a0 = A[r0], a1 = A[r1];
              A[r0] = c*a0 - s*a1;
              A[r1] = s*a0 + c*a1;
            }
        } else {
          constexpr int LM = 1 << (G.ba - 4);
          const float sg = ((lane >> (G.ba - 4)) & 1) ? s : -s;
#pragma unroll
          for (int r = 0; r < 16; r++) {
            v2f p = shfl2(A[r], LM);
            A[r] = c*A[r] + sg*p;
          }
        }
      } else {
        // ---- RZ: diagonal phase, NO shuffles ----
        if constexpr (G.ba < 4) {
#pragma unroll
          for (int r = 0; r < 16; r++) {
            const float u = ((r >> G.ba) & 1) ? -s : s;
            A[r] = c*A[r] + u*jmul(A[r]);
          }
        } else {
          const float u = ((lane >> (G.ba - 4)) & 1) ? -s : s;
#pragma unroll
          for (int r = 0; r < 16; r++)
            A[r] = c*A[r] + u*jmul(A[r]);
        }
      }
    }
    apply_rand<GI + 1>(A, ws, lane);
  }
}

// ---------------------------------------------------------------------------
// Main sim kernel: one wave per batch element, 16 packed complex amps/lane.
// flat = lane*16 + r; flat bit b<4 -> reg bit; b>=4 -> lane bit b-4.
// wire w <-> flat bit 9-w.
// Tail (RX,RY on all wires) folded into the measurement operator O = M^dag Z M
// (M unitary => gates on other wires cancel). Head folded into the per-lane
// accumulator => single butterfly reduction.
// ---------------------------------------------------------------------------
__global__ __launch_bounds__(256) void qsim_kernel(
    const float* __restrict__ x,
    const float* __restrict__ ws,
    const float* __restrict__ head_w,
    const float* __restrict__ head_b,
    float* __restrict__ out,
    int bsz)
{
  const int wv = (int)((blockIdx.x * blockDim.x + threadIdx.x) >> 6);
  const int lane = (int)(threadIdx.x & 63);
  if (wv >= bsz) return;
  const float* xe = x + wv * NW;

  // ---- Encoder: product state from RY(x_w)|0> ----
  float cw[NW], sw[NW];
#pragma unroll
  for (int w = 0; w < NW; w++) {
    float xv = xe[w] * 0.5f;
    cw[w] = __cosf(xv);
    sw[w] = __sinf(xv);
  }
  float pl = 1.0f;
#pragma unroll
  for (int lb = 0; lb < 6; lb++)      // lane bit lb <-> wire 5-lb
    pl *= ((lane >> lb) & 1) ? sw[5 - lb] : cw[5 - lb];

  v2f A[16];
#pragma unroll
  for (int r = 0; r < 16; r++) {      // reg bit rb <-> wire 9-rb
    float p = pl;
    p *= ((r >> 0) & 1) ? sw[9] : cw[9];
    p *= ((r >> 1) & 1) ? sw[8] : cw[8];
    p *= ((r >> 2) & 1) ? sw[7] : cw[7];
    p *= ((r >> 3) & 1) ? sw[6] : cw[6];
    A[r] = (v2f){p, 0.f};
  }

  // ---- Random section (compile-time unrolled, specialized) ----
  apply_rand<0>(A, ws, lane);

  // ---- Measurement: <O_w> with O = [[a, b],[conj(b), -a]] ----
  const float a  = ws[72];
  const float br = ws[73];
  const float bi = ws[74];

  // probs and reg-bit signed sums
  float p[16];
  float S = 0.f, zr0 = 0.f, zr1 = 0.f, zr2 = 0.f, zr3 = 0.f;
#pragma unroll
  for (int r = 0; r < 16; r++) {
    v2f sq = A[r] * A[r];
    p[r] = sq.x + sq.y;
    S += p[r];
    zr0 += ((r >> 0) & 1) ? -p[r] : p[r];   // wire 9
    zr1 += ((r >> 1) & 1) ? -p[r] : p[r];   // wire 8
    zr2 += ((r >> 2) & 1) ? -p[r] : p[r];   // wire 7
    zr3 += ((r >> 3) & 1) ? -p[r] : p[r];   // wire 6
  }

  float acc = 0.f;

  // Reg-bit wires: wire 9-j for reg bit j. Pairs fully local -> factor 2.
#pragma unroll
  for (int j = 0; j < 4; j++) {
    const int MK = 1 << j;
    float Cr = 0.f, Ci = 0.f;
#pragma unroll
    for (int r0 = 0; r0 < 16; r0++)
      if (!(r0 & MK)) {
        const int r1 = r0 | MK;
        Cr += A[r0].x * A[r1].x + A[r0].y * A[r1].y;  // Re(conj(ps0)*ps1)
        Ci += A[r0].x * A[r1].y - A[r0].y * A[r1].x;  // Im(conj(ps0)*ps1)
      }
    const float zj = (j == 0) ? zr0 : (j == 1) ? zr1 : (j == 2) ? zr2 : zr3;
    acc += head_w[9 - j] * (a * zj + 2.f * (br * Cr - bi * Ci));
  }

  // Lane-bit wires: wire 5-lb for lane bit lb. Per-lane half contributions
  // (the two partner lanes' contributions sum to the full pair term).
#pragma unroll
  for (int lb = 0; lb < 6; lb++) {
    const int m = 1 << lb;
    const int bit = (lane >> lb) & 1;
    float qr = 0.f, qi = 0.f;
#pragma unroll
    for (int r = 0; r < 16; r++) {
      v2f pp = shfl2(A[r], m);
      qr += A[r].x * pp.x + A[r].y * pp.y;   // Re(conj(loc)*partner)
      qi += A[r].x * pp.y - A[r].y * pp.x;   // Im(conj(loc)*partner)
    }
    const float sbi = bit ? bi : -bi;
    const float sa  = bit ? -a : a;
    acc += head_w[5 - lb] * (sa * S + br * qr + sbi * qi);
  }

  // Single butterfly reduction of the folded head dot-product
#pragma unroll
  for (int m = 1; m < 64; m <<= 1) acc += __shfl_xor(acc, m);

  if (lane == 0) {
    float cc = ws[80 + NW] + head_b[0];
#pragma unroll
    for (int w = 0; w < NW; w++) cc += xe[w] * ws[80 + w];
    out[wv] = acc + cc;
  }
}

extern "C" void kernel_launch(void* const* d_in, const int* in_sizes, int n_in,
                              void* d_out, int out_size, void* d_ws, size_t ws_size,
                              hipStream_t stream) {
  const float* x   = (const float*)d_in[0];
  const float* rp  = (const float*)d_in[1];
  const float* rxT = (const float*)d_in[2];
  const float* ryT = (const float*)d_in[3];
  const float* hw  = (const float*)d_in[4];
  const float* hb  = (const float*)d_in[5];
  const float* w0  = (const float*)d_in[6];
  const float* b0  = (const float*)d_in[7];
  const float* w1  = (const float*)d_in[8];
  const float* b1  = (const float*)d_in[9];
  const float* w2  = (const float*)d_in[10];
  const float* b2  = (const float*)d_in[11];
  const float* w3  = (const float*)d_in[12];
  const float* b3  = (const float*)d_in[13];
  const int bsz = in_sizes[0] / NW;

  float* ws = (float*)d_ws;

  hipLaunchKernelGGL(prep_kernel, dim3(1), dim3(64), 0, stream,
                     rp, rxT, ryT, w0, b0, w1, b1, w2, b2, w3, b3, ws);

  const int blocks = (bsz + 3) / 4; // 4 waves per 256-thread block
  hipLaunchKernelGGL(qsim_kernel, dim3(blocks), dim3(256), 0, stream,
                     x, ws, hw, hb, (float*)d_out, bsz);
}

// Round 10
// 93.277 us; speedup vs baseline: 1.8024x; 1.4235x over previous
//
#include <hip/hip_runtime.h>
#include <cstdint>

#define NW 10
#define NOPS 30

// ---------------------------------------------------------------------------
// Constexpr numpy RNG (SeedSequence + PCG64 XSL-RR), canary-certified (R5/R6).
// ---------------------------------------------------------------------------
namespace {

typedef unsigned __int128 u128;

struct CRng { u128 state; u128 inc; bool has32; uint32_t cached; };

constexpr u128 PCG_MUL = (((u128)0x2360ED051FC65DA4ULL) << 64) | (u128)0x4385DF649FCCF645ULL;

constexpr void cr_step(CRng &r) { r.state = r.state * PCG_MUL + r.inc; }

constexpr uint64_t cr_out(u128 st) {
  uint64_t hi = (uint64_t)(st >> 64);
  uint64_t lo = (uint64_t)st;
  unsigned rot = (unsigned)(st >> 122) & 63u;
  uint64_t v = hi ^ lo;
  return (v >> rot) | (v << ((64u - rot) & 63u));
}

constexpr uint64_t cr_next64(CRng &r) { cr_step(r); return cr_out(r.state); }

constexpr uint32_t cr_next32(CRng &r) {
  if (r.has32) { r.has32 = false; return r.cached; }
  uint64_t v = cr_next64(r);
  r.has32 = true; r.cached = (uint32_t)(v >> 32);
  return (uint32_t)v;
}

constexpr CRng cr_seed(uint32_t ent) {
  uint32_t pool[4] = {0u, 0u, 0u, 0u};
  uint32_t hc = 0x43b0d7e5u;              // INIT_A
  for (int i = 0; i < 4; i++) {
    uint32_t v = (i == 0) ? ent : 0u;
    v ^= hc; hc *= 0x931e8875u; v *= hc; v ^= v >> 16;
    pool[i] = v;
  }
  for (int s = 0; s < 4; s++)
    for (int d = 0; d < 4; d++)
      if (s != d) {
        uint32_t v = pool[s];
        v ^= hc; hc *= 0x931e8875u; v *= hc; v ^= v >> 16;        // hashmix
        uint32_t res = 0xca01f9ddu * pool[d] - 0x4973f715u * v;   // mix (SUB)
        res ^= res >> 16;
        pool[d] = res;
      }
  uint32_t hb = 0x8b51f9ddu;              // INIT_B
  uint64_t s64[4] = {0ull, 0ull, 0ull, 0ull};
  for (int i = 0; i < 8; i++) {
    uint32_t d = pool[i & 3];
    d ^= hb; hb *= 0x58f38dedu; d *= hb; d ^= d >> 16;
    if (i & 1) s64[i >> 1] |= ((uint64_t)d << 32); else s64[i >> 1] = (uint64_t)d;
  }
  CRng r{};
  u128 initstate = (((u128)s64[0]) << 64) | (u128)s64[1];
  u128 initseq   = (((u128)s64[2]) << 64) | (u128)s64[3];
  r.state = 0; r.inc = (initseq << 1) | (u128)1;
  cr_step(r);
  r.state += initstate;
  cr_step(r);
  r.has32 = false; r.cached = 0u;
  return r;
}

constexpr uint32_t cr_lemire32(CRng &r, uint32_t rng) {
  uint32_t rng_excl = rng + 1u;
  uint64_t m = (uint64_t)cr_next32(r) * (uint64_t)rng_excl;
  uint32_t leftover = (uint32_t)m;
  if (leftover < rng_excl) {
    uint32_t threshold = (uint32_t)(0xFFFFFFFFu - rng) % rng_excl;
    while (leftover < threshold) {
      m = (uint64_t)cr_next32(r) * (uint64_t)rng_excl;
      leftover = (uint32_t)m;
    }
  }
  return (uint32_t)(m >> 32);
}

constexpr bool canary_pcg42() {
  CRng r = cr_seed(42u);
  double a = (double)(cr_next64(r) >> 11) * (1.0 / 9007199254740992.0);
  double b = (double)(cr_next64(r) >> 11) * (1.0 / 9007199254740992.0);
  double c = (double)(cr_next64(r) >> 11) * (1.0 / 9007199254740992.0);
  bool ok = (a > 0.77395603) && (a < 0.77395607);
  ok = ok && (b > 0.43887842) && (b < 0.43887846);
  ok = ok && (c > 0.85859790) && (c < 0.85859794);
  return ok;
}
static_assert(canary_pcg42(), "CANARY_PCG_SEED42_RANDOM_MISMATCH");

// ---- compile-time circuit (WIRE indices; kind 0 RX,1 RY,2 RZ,3 CNOT) ------
struct COp { int kind; int a; int b; int slot; };
struct Circ { COp op[NOPS]; };

constexpr Circ build_circuit() {
  Circ c{};
  CRng r = cr_seed(42u);
  for (int i = 0; i < NOPS; i++) {
    int k = (int)cr_lemire32(r, 3u);            // integers(0,4)
    if (k == 3) {
      uint32_t v8 = cr_lemire32(r, 8u);         // Floyd j=8
      uint32_t v9 = cr_lemire32(r, 9u);         // Floyd j=9
      uint32_t i0 = v8;
      uint32_t i1 = (v9 == v8) ? 9u : v9;
      uint32_t j = cr_lemire32(r, 1u);          // shuffle swap bit
      if (j == 0u) { uint32_t t = i0; i0 = i1; i1 = t; }
      c.op[i] = COp{3, (int)i0, (int)i1, i};    // a=control, b=target
    } else {
      int w = (int)cr_lemire32(r, 9u);          // integers(0,10)
      c.op[i] = COp{k, w, 0, i};
    }
  }
  return c;
}
constexpr Circ CC = build_circuit();

// ---------------------------------------------------------------------------
// Compile-time Heisenberg propagation of H = sum_w hw_w (cZ Z_w + cX X_w +
// cY Y_w) backward through the 30 ops. Strings in symplectic form
// (xm,zm 10 bits each), sign tracked; rotations split non-commuting strings
// into cos/sin branches (Q -> cos t Q + sin t (iPQ)); CNOT is Clifford
// (sign flip iff x_c & z_t & (x_t==z_c); x_t^=x_c, z_c^=z_t).
// Y-containing final strings dropped (<Y>=0 for the real product state).
// meta: xm[0:10) | zm[10:20) | sign[20] | w[21:25) | src[25:27)
// ---------------------------------------------------------------------------
constexpr int MAXP = 16384;
constexpr int MAXU = 4096;

struct Tables {
  int np, nu, overflow;
  uint32_t pmeta[MAXP]; uint32_t pcm[MAXP]; uint32_t psm[MAXP];
  uint32_t ukey[MAXU];  int ustart[MAXU + 1];
};

constexpr Tables build_tables() {
  Tables T{};
  uint32_t meta[MAXP] = {}; uint32_t cm[MAXP] = {}; uint32_t sm[MAXP] = {};
  int np = 0; int ovf = 0;
  for (int w = 0; w < NW; w++)
    for (int src = 0; src < 3; src++) {         // 0:cZ->Z, 1:cX->X, 2:cY->Y
      uint32_t xm = (src != 0) ? (1u << w) : 0u;
      uint32_t zm = (src != 1) ? (1u << w) : 0u;
      meta[np] = xm | (zm << 10) | ((uint32_t)w << 21) | ((uint32_t)src << 25);
      cm[np] = 0u; sm[np] = 0u; np++;
    }
  for (int k = NOPS - 1; k >= 0 && !ovf; k--) {
    const COp op = CC.op[k];
    if (op.kind == 3) {
      const int c = op.a, t = op.b;
      for (int p = 0; p < np; p++) {
        uint32_t m = meta[p];
        uint32_t xm = m & 1023u, zm = (m >> 10) & 1023u;
        uint32_t xc = (xm >> c) & 1u, zc = (zm >> c) & 1u;
        uint32_t xt = (xm >> t) & 1u, zt = (zm >> t) & 1u;
        uint32_t fl = xc & zt & (1u ^ (xt ^ zc));
        xm ^= xc << t;
        zm ^= zt << c;
        m = (m & ~(1023u | (1023u << 10))) | xm | (zm << 10);
        m ^= fl << 20;
        meta[p] = m;
      }
    } else {
      const int q = op.a, ax = op.kind, bit = op.slot;
      const int n0 = np;
      for (int p = 0; p < n0; p++) {
        uint32_t m = meta[p];
        uint32_t x = (m >> q) & 1u;
        uint32_t z = (m >> (10 + q)) & 1u;
        uint32_t viol = (ax == 0) ? z : (ax == 1) ? (x ^ z) : x;
        if (viol) {
          uint32_t nx = 0, nz = 0, fl = 0;
          if (ax == 0)      { if (x) { nx = 0; nz = 1; fl = 1; } else { nx = 1; nz = 1; fl = 0; } }
          else if (ax == 1) { if (x) { nx = 0; nz = 1; fl = 0; } else { nx = 1; nz = 0; fl = 1; } }
          else              { if (z) { nx = 1; nz = 0; fl = 0; } else { nx = 1; nz = 1; fl = 1; } }
          if (np >= MAXP) { ovf = 1; break; }
          uint32_t m2 = m;
          m2 &= ~((1u << q) | (1u << (10 + q)));
          m2 |= (nx << q) | (nz << (10 + q));
          m2 ^= fl << 20;
          meta[np] = m2; cm[np] = cm[p]; sm[np] = sm[p] | (1u << bit);
          np++;
          cm[p] |= 1u << bit;
        }
      }
    }
  }
  if (ovf) { T.overflow = 1; return T; }
  // Y-kill compact
  int n2 = 0;
  for (int p = 0; p < np; p++) {
    uint32_t m = meta[p];
    if ((m & 1023u) & ((m >> 10) & 1023u)) continue;
    meta[n2] = m; cm[n2] = cm[p]; sm[n2] = sm[p]; n2++;
  }
  np = n2;
  // stable 2-pass radix sort of indices by 20-bit key
  int idx[MAXP] = {}; int tmp[MAXP] = {};
  for (int i = 0; i < np; i++) idx[i] = i;
  int hist[1025] = {};
  for (int i = 0; i < 1025; i++) hist[i] = 0;
  for (int i = 0; i < np; i++) hist[1 + (meta[idx[i]] & 1023u)]++;
  for (int i = 0; i < 1024; i++) hist[i + 1] += hist[i];
  for (int i = 0; i < np; i++) tmp[hist[meta[idx[i]] & 1023u]++] = idx[i];
  for (int i = 0; i < 1025; i++) hist[i] = 0;
  for (int i = 0; i < np; i++) hist[1 + ((meta[tmp[i]] >> 10) & 1023u)]++;
  for (int i = 0; i < 1024; i++) hist[i + 1] += hist[i];
  for (int i = 0; i < np; i++) idx[hist[(meta[tmp[i]] >> 10) & 1023u]++] = tmp[i];
  // group + emit
  int nu = 0; uint32_t prev = 0xFFFFFFFFu;
  for (int i = 0; i < np; i++) {
    int p = idx[i];
    uint32_t key = meta[p] & 0xFFFFFu;
    if (key != prev) {
      if (nu >= MAXU) { T.overflow = 2; return T; }
      T.ukey[nu] = key; T.ustart[nu] = i; prev = key; nu++;
    }
    T.pmeta[i] = meta[p]; T.pcm[i] = cm[p]; T.psm[i] = sm[p];
  }
  T.ustart[nu] = np;
  T.np = np; T.nu = nu; T.overflow = 0;
  return T;
}

constexpr Tables TT = build_tables();
static_assert(TT.overflow == 0, "PAULI_PATH_OVERFLOW_raise_MAXP_or_pivot_to_runtime_tables");
static_assert(TT.nu >= 1 && TT.nu <= MAXU, "PAULI_UNIQUE_COUNT_OUT_OF_RANGE");
constexpr int NU = TT.nu;

} // namespace

__device__ const Tables dTT = TT;

// ---------------------------------------------------------------------------
// Prep kernel (1 block x 256): trig of the 30 angles + tail-fold Pauli coeffs
// (cZ,cX,cY) + per-unique-string coefficients C_u -> ws[0..NU); MLP collapse
// W_eff,const -> ws[NU..NU+10], ws[NU+10] (includes b_eff + head_b).
// ---------------------------------------------------------------------------
__global__ __launch_bounds__(256) void prep_kernel(
    const float* __restrict__ rand_params,
    const float* __restrict__ rx_theta, const float* __restrict__ ry_theta,
    const float* __restrict__ head_w, const float* __restrict__ head_b,
    const float* __restrict__ w0, const float* __restrict__ b0,
    const float* __restrict__ w1, const float* __restrict__ b1,
    const float* __restrict__ w2, const float* __restrict__ b2,
    const float* __restrict__ w3, const float* __restrict__ b3,
    float* __restrict__ ws)
{
  const int tid = threadIdx.x;
  __shared__ float ct[32], st[32], abr[3], hwsh[10];
  __shared__ float r2[32], r1[64];

  if (tid < NOPS) {
    float t = rand_params[tid];       // FULL angle for Heisenberg conjugation
    ct[tid] = cosf(t);
    st[tid] = sinf(t);
  }
  if (tid == 30) {
    // O = M^dag Z M for M = RY(ty) @ RX(tx), in PAULI coefficients:
    //   O = cZ*Z + cX*X + cY*Y
    //   cZ = cos tx cos ty ; cX = -sin ty ; cY = +sin tx cos ty
    // (R9 BUG: used bi = -sx*cy as Y coeff; correct Pauli coeff is -bi.
    //  Cross-checked vs R8's HW-verified  a*<Z> + br*<X> - bi*<Y>.)
    float tx = rx_theta[0], ty = ry_theta[0];
    abr[0] = cosf(tx) * cosf(ty);     // cZ
    abr[1] = -sinf(ty);               // cX
    abr[2] = sinf(tx) * cosf(ty);     // cY  (= -bi)
  }
  if (tid < NW) hwsh[tid] = head_w[tid];
  __syncthreads();

  for (int u = tid; u < NU; u += 256) {
    float acc = 0.f;
    const int i0 = dTT.ustart[u], i1 = dTT.ustart[u + 1];
    for (int i = i0; i < i1; i++) {
      uint32_t m = dTT.pmeta[i];
      float v = hwsh[(m >> 21) & 15u] * abr[(m >> 25) & 3u];
      if (m & (1u << 20)) v = -v;
      uint32_t c = dTT.pcm[i];
      while (c) { int b = __builtin_ctz(c); v *= ct[b]; c &= c - 1u; }
      uint32_t s = dTT.psm[i];
      while (s) { int b = __builtin_ctz(s); v *= st[b]; s &= s - 1u; }
      acc += v;
    }
    ws[u] = acc;
  }

  // ---- MLP collapse (fully linear) ----
  if (tid < 32) {
    float acc = 0.f;
    for (int k = 0; k < 16; k++) acc += w3[k] * w2[k*32 + tid];
    r2[tid] = acc;
  }
  __syncthreads();
  if (tid < 64) {
    float acc = 0.f;
    for (int k = 0; k < 32; k++) acc += r2[k] * w1[k*64 + tid];
    r1[tid] = acc;
  }
  __syncthreads();
  if (tid < NW) {
    float acc = 0.f;
    for (int k = 0; k < 64; k++) acc += r1[k] * w0[k*NW + tid];
    ws[NU + tid] = acc;
  }
  if (tid == NW) {
    float acc = b3[0] + head_b[0];
    for (int k = 0; k < 16; k++) acc += w3[k] * b2[k];
    for (int k = 0; k < 32; k++) acc += r2[k] * b1[k];
    for (int k = 0; k < 64; k++) acc += r1[k] * b0[k];
    ws[NU + NW] = acc;
  }
}

// ---------------------------------------------------------------------------
// Eval kernel: one 64-lane wave per element; unique strings strided across
// lanes from LDS. q(x) = sum_u C_u * prod_w [xbit? sin x_w : zbit? cos x_w : 1]
// then one butterfly reduction; + collapsed-MLP linear term.
// ---------------------------------------------------------------------------
__global__ __launch_bounds__(256) void qsim_kernel(
    const float* __restrict__ x,
    const float* __restrict__ ws,
    float* __restrict__ out,
    int bsz)
{
  __shared__ float    Csh[NU];
  __shared__ uint32_t Ksh[NU];
  const int tid = threadIdx.x;
  for (int i = tid; i < NU; i += 256) {
    Csh[i] = ws[i];
    Ksh[i] = dTT.ukey[i];
  }
  __syncthreads();

  const int wv = (int)((blockIdx.x * blockDim.x + tid) >> 6);
  const int lane = tid & 63;
  if (wv >= bsz) return;
  const float* xe = x + wv * NW;

  float cz[NW], sx[NW];
#pragma unroll
  for (int w = 0; w < NW; w++) {
    float xv = xe[w];
    cz[w] = __cosf(xv);
    sx[w] = __sinf(xv);
  }

  float acc = 0.f;
  for (int s = lane; s < NU; s += 64) {
    uint32_t k = Ksh[s];
    float v = Csh[s];
#pragma unroll
    for (int w = 0; w < NW; w++) {
      float f = ((k >> w) & 1u) ? sx[w]
              : (((k >> (10 + w)) & 1u) ? cz[w] : 1.0f);
      v *= f;
    }
    acc += v;
  }

#pragma unroll
  for (int m = 1; m < 64; m <<= 1) acc += __shfl_xor(acc, m);

  if (lane == 0) {
    float cc = ws[NU + NW];
#pragma unroll
    for (int w = 0; w < NW; w++) cc += xe[w] * ws[NU + w];
    out[wv] = acc + cc;
  }
}

extern "C" void kernel_launch(void* const* d_in, const int* in_sizes, int n_in,
                              void* d_out, int out_size, void* d_ws, size_t ws_size,
                              hipStream_t stream) {
  const float* x   = (const float*)d_in[0];
  const float* rp  = (const float*)d_in[1];
  const float* rxT = (const float*)d_in[2];
  const float* ryT = (const float*)d_in[3];
  const float* hw  = (const float*)d_in[4];
  const float* hb  = (const float*)d_in[5];
  const float* w0  = (const float*)d_in[6];
  const float* b0  = (const float*)d_in[7];
  const float* w1  = (const float*)d_in[8];
  const float* b1  = (const float*)d_in[9];
  const float* w2  = (const float*)d_in[10];
  const float* b2  = (const float*)d_in[11];
  const float* w3  = (const float*)d_in[12];
  const float* b3  = (const float*)d_in[13];
  const int bsz = in_sizes[0] / NW;

  float* ws = (float*)d_ws;

  hipLaunchKernelGGL(prep_kernel, dim3(1), dim3(256), 0, stream,
                     rp, rxT, ryT, hw, hb, w0, b0, w1, b1, w2, b2, w3, b3, ws);

  const int blocks = (bsz + 3) / 4; // 4 elements (waves) per 256-thread block
  hipLaunchKernelGGL(qsim_kernel, dim3(blocks), dim3(256), 0, stream,
                     x, ws, (float*)d_out, bsz);
}